// Round 14
// baseline (114.442 us; speedup 1.0000x reference)
//
#include <hip/hip_runtime.h>
#include <hip/hip_bf16.h>
#include <stdint.h>

// Problem constants (fixed by reference)
#define NB    8
#define NS    2048
#define NE    1024
#define NH    16
#define NDK   64
#define MTOK  (NB*NS)      // 16384 tokens

typedef __attribute__((ext_vector_type(8))) short bf16x8;
typedef __attribute__((ext_vector_type(4))) float f32x4;

// round-to-nearest-even f32 -> bf16 bits
__device__ __forceinline__ ushort f2bf(float f) {
  uint32_t u = __float_as_uint(f);
  u += 0x7FFFu + ((u >> 16) & 1u);
  return (ushort)(u >> 16);
}

__device__ __forceinline__ void gload16(const void* g, void* l) {
  __builtin_amdgcn_global_load_lds(
      (const __attribute__((address_space(1))) void*)g,
      (__attribute__((address_space(3))) void*)l, 16, 0, 0);
}

// ---------------- f32 -> bf16 cast (vectorized; W only) ----------------
__global__ __launch_bounds__(256) void cvt_bf16(const float* __restrict__ in,
                                                ushort* __restrict__ out, int n4) {
  int stride = gridDim.x * blockDim.x;
  for (int j = blockIdx.x * blockDim.x + threadIdx.x; j < n4; j += stride) {
    float4 v = ((const float4*)in)[j];
    ushort4 o;
    o.x = f2bf(v.x); o.y = f2bf(v.y); o.z = f2bf(v.z); o.w = f2bf(v.w);
    ((ushort4*)out)[j] = o;
  }
}

#define KC 1024
#define NKT 16   // KC / 64

// ======================= GEMM1: qq = cosq(x @ Wb^T) =========================
// Tile 128x256, BK=64, 8 waves (2M x 4N -> 64x64/wave), acc[4][4] = 64 AGPR.
// A = x (f32) REG-STAGED two tiles ahead: loadA(t+2)->regs at q0(t); at q3(t)
// vmcnt(4) (drains B(t+1) [3 phases old] + A-regs(t+1) [7 phases old], leaves
// A-regs(t+2)), RNE cvt + 2x ds_write_b128 swizzled, lgkmcnt(0), barrier.
// B bf16 via global_load_lds (source-inverse swizzle, linear LDS dest).
// ONE barrier per K-tile (q3-end) — tile-t reads all complete before each
// wave reaches it; buffer nb is written only by WRITEA/stB of tile t.
// LDS 96 KB: As[2][128][64]bf16 (32K) + Bs[2][256][64] (64K).
// Register fit (R9/R10 lesson): 64 AGPR acc + 32 VGPR arP/arQ + frags ~ fits
// the 8-wave budget; no scratch spill expected.
#define QM 128
#define QN 256
#define QK 64

#define LOADAQ(kt, AR)                                                        \
  do {                                                                        \
    _Pragma("unroll")                                                         \
    for (int j = 0; j < 4; ++j)                                               \
      AR[j] = X4[(size_t)(br * QM + ar_r) * 256 + (kt) * 16 + c4 * 4 + j];    \
  } while (0)

#define WRITEAQ(buf, AR)                                                      \
  do {                                                                        \
    bf16x8 v0, v1;                                                            \
    v0[0] = (short)f2bf(AR[0].x); v0[1] = (short)f2bf(AR[0].y);               \
    v0[2] = (short)f2bf(AR[0].z); v0[3] = (short)f2bf(AR[0].w);               \
    v0[4] = (short)f2bf(AR[1].x); v0[5] = (short)f2bf(AR[1].y);               \
    v0[6] = (short)f2bf(AR[1].z); v0[7] = (short)f2bf(AR[1].w);               \
    v1[0] = (short)f2bf(AR[2].x); v1[1] = (short)f2bf(AR[2].y);               \
    v1[2] = (short)f2bf(AR[2].z); v1[3] = (short)f2bf(AR[2].w);               \
    v1[4] = (short)f2bf(AR[3].x); v1[5] = (short)f2bf(AR[3].y);               \
    v1[6] = (short)f2bf(AR[3].z); v1[7] = (short)f2bf(AR[3].w);               \
    *(bf16x8*)&As[buf][ar_r * QK + wrs0] = v0;                                \
    *(bf16x8*)&As[buf][ar_r * QK + wrs1] = v1;                                \
  } while (0)

#define QMFMA(MOFF)                                                           \
  __builtin_amdgcn_sched_barrier(0);                                          \
  __builtin_amdgcn_s_setprio(1);                                              \
  _Pragma("unroll")                                                           \
  for (int mi = 0; mi < 2; ++mi)                                              \
    _Pragma("unroll")                                                         \
    for (int ni = 0; ni < 4; ++ni)                                            \
      acc[mi + (MOFF)][ni] = __builtin_amdgcn_mfma_f32_16x16x32_bf16(         \
          af[mi], bv[ni], acc[mi + (MOFF)][ni], 0, 0, 0);                     \
  __builtin_amdgcn_s_setprio(0);                                              \
  __builtin_amdgcn_sched_barrier(0);

#define BODYQ(T, ARL, ARW)                                                    \
  {                                                                           \
    const int t = (T);                                                        \
    const ushort* Ac = As[cur];                                               \
    const ushort* Bc = Bs[cur];                                               \
    const int nb = cur ^ 1;                                                   \
    const bool pf  = (t + 1 < NKT);                                           \
    const bool pf2 = (t + 2 < NKT);                                           \
    bf16x8 af[2], bv[4];                                                      \
    /* q0: kk0, mi{0,1}; stage B(t+1); issue A-loads(t+2) */                  \
    _Pragma("unroll")                                                         \
    for (int mi = 0; mi < 2; ++mi)                                            \
      af[mi] = *(const bf16x8*)&Ac[(wr * 64 + mi * 16 + fr) * QK + sA0];      \
    _Pragma("unroll")                                                         \
    for (int ni = 0; ni < 4; ++ni)                                            \
      bv[ni] = *(const bf16x8*)&Bc[(ni * 64 + wc * 16 + fr) * QK + sA0];      \
    if (pf) { stB(nb, 0, t + 1); stB(nb, 1, t + 1); }                         \
    if (pf2) LOADAQ(t + 2, ARL);                                              \
    QMFMA(0)                                                                  \
    /* q1: kk0, mi{2,3} (bv kept in regs) */                                  \
    _Pragma("unroll")                                                         \
    for (int mi = 0; mi < 2; ++mi)                                            \
      af[mi] = *(const bf16x8*)&Ac[(wr * 64 + (mi + 2) * 16 + fr) * QK + sA0];\
    QMFMA(2)                                                                  \
    /* q2: kk1, mi{0,1} */                                                    \
    _Pragma("unroll")                                                         \
    for (int mi = 0; mi < 2; ++mi)                                            \
      af[mi] = *(const bf16x8*)&Ac[(wr * 64 + mi * 16 + fr) * QK + sA1];      \
    _Pragma("unroll")                                                         \
    for (int ni = 0; ni < 4; ++ni)                                            \
      bv[ni] = *(const bf16x8*)&Bc[(ni * 64 + wc * 16 + fr) * QK + sA1];      \
    QMFMA(0)                                                                  \
    /* q3: kk1, mi{2,3}; land A(t+1) into LDS */                              \
    _Pragma("unroll")                                                         \
    for (int mi = 0; mi < 2; ++mi)                                            \
      af[mi] = *(const bf16x8*)&Ac[(wr * 64 + (mi + 2) * 16 + fr) * QK + sA1];\
    QMFMA(2)                                                                  \
    if (pf) {                                                                 \
      if (pf2) asm volatile("s_waitcnt vmcnt(4)" ::: "memory");               \
      else     asm volatile("s_waitcnt vmcnt(0)" ::: "memory");               \
      WRITEAQ(nb, ARW);                                                       \
      asm volatile("s_waitcnt lgkmcnt(0)" ::: "memory");                      \
    }                                                                         \
    __builtin_amdgcn_s_barrier();                                             \
    cur ^= 1;                                                                 \
  }

__global__ __launch_bounds__(512, 1) void gemm_xq(const float* __restrict__ X,
                                                  const ushort* __restrict__ Bm,
                                                  ushort* __restrict__ Cq,
                                                  const float* __restrict__ theta) {
  __shared__ ushort As[2][QM * QK];   // 16 KB per buffer
  __shared__ ushort Bs[2][QN * QK];   // 32 KB per buffer

  const int tid  = threadIdx.x;
  const int wid  = tid >> 6;
  const int lane = tid & 63;
  const int wr   = wid >> 2;        // 0..1  (M half)
  const int wc   = wid & 3;         // 0..3  (N quarter)
  const int fr   = lane & 15;
  const int ks   = lane >> 4;       // 0..3

  // XCD-chunked bijective swizzle: 512 blocks, 64 per XCD (16 br x 4 bc)
  int b  = blockIdx.x;
  int wg = ((b & 7) << 6) | (b >> 3);
  int br = wg >> 2, bc = wg & 3;

  const ushort* Bbase = Bm + (size_t)(bc * QN) * KC;
  const float4* X4    = (const float4*)X;

  // B gload staging constants (same convention as gemm256)
  const int srow = lane >> 3;
  const int sch8 = ((lane & 7) ^ srow) * 8;

  // A reg-stage: thread covers row ar_r, k-chunks {2c4, 2c4+1} (16 f32)
  const int ar_r = wid * 16 + (lane >> 2);   // 0..127
  const int c4   = lane & 3;
  const int wrs0 = ((2 * c4)     ^ (ar_r & 7)) * 8;
  const int wrs1 = ((2 * c4 + 1) ^ (ar_r & 7)) * 8;

  // ds_read slot offsets: chunk = kk*4+ks, slot = chunk ^ (row&7), row&7==fr&7
  const int sA0 = ((0 + ks) ^ (fr & 7)) * 8;
  const int sA1 = ((4 + ks) ^ (fr & 7)) * 8;

  f32x4 zero = {0.f, 0.f, 0.f, 0.f};
  f32x4 acc[4][4];
#pragma unroll
  for (int mi = 0; mi < 4; ++mi)
#pragma unroll
    for (int ni = 0; ni < 4; ++ni) acc[mi][ni] = zero;

  auto stB = [&](int buf, int mh, int kt) {
#pragma unroll
    for (int j = 0; j < 2; ++j) {
      int rl = mh * 128 + j * 64 + wid * 8;
      gload16(Bbase + (size_t)(rl + srow) * KC + kt * QK + sch8,
              &Bs[buf][rl * QK]);
    }
  };

  float4 arP[4], arQ[4];

  // ---- prologue ----
  LOADAQ(0, arP);
  asm volatile("s_waitcnt vmcnt(0)" ::: "memory");
  WRITEAQ(0, arP);
  stB(0, 0, 0); stB(0, 1, 0);
  LOADAQ(1, arQ);
  asm volatile("s_waitcnt vmcnt(4)" ::: "memory");   // B(0) landed; A(1) in flight
  asm volatile("s_waitcnt lgkmcnt(0)" ::: "memory"); // A(0) LDS writes drained
  __builtin_amdgcn_s_barrier();

  int cur = 0;
  for (int t2 = 0; t2 < NKT; t2 += 2) {
    BODYQ(t2,     arP, arQ)   // loads A(t2+2)->arP, writes A(t2+1) from arQ
    BODYQ(t2 + 1, arQ, arP)
  }

  // ---- epilogue: qq = cos(theta[col&63]) * cos(acc) -> bf16 ----
  const int colL = wc * 16 + fr;
  float ct = __cosf(theta[colL]);
#pragma unroll
  for (int mi = 0; mi < 4; ++mi) {
    int row0 = br * QM + wr * 64 + mi * 16 + ks * 4;
#pragma unroll
    for (int ni = 0; ni < 4; ++ni) {
      size_t cbase = (size_t)row0 * NE + bc * QN + ni * 64 + colL;
#pragma unroll
      for (int i = 0; i < 4; ++i)
        Cq[cbase + (size_t)i * NE] = f2bf(ct * __cosf(acc[mi][ni][i]));
    }
  }
}

// ======================= GEMM2 (r13, proven): out = aout @ Wb^T ==============
#define GM 256
#define GN 256
#define GK 64

template<int EPI>
__global__ __launch_bounds__(512, 2) void gemm256(const ushort* __restrict__ A,
                                                  const ushort* __restrict__ Bm,
                                                  float* __restrict__ Cf,
                                                  ushort* __restrict__ Cq,
                                                  const float* __restrict__ theta,
                                                  int M, int N, int K) {
  __shared__ ushort As[2][GM * GK];
  __shared__ ushort Bs[2][GN * GK];

  const int tid  = threadIdx.x;
  const int wid  = tid >> 6;
  const int lane = tid & 63;
  const int wr   = wid >> 2;
  const int wc   = wid & 3;
  const int fr   = lane & 15;
  const int ks   = lane >> 4;

  int b  = blockIdx.x;
  int wg = ((b & 7) << 5) | (b >> 3);
  int br = wg >> 2, bc = wg & 3;

  const ushort* Abase = A  + (size_t)(br * GM) * KC;
  const ushort* Bbase = Bm + (size_t)(bc * GN) * KC;

  const int srow = lane >> 3;
  const int sch8 = ((lane & 7) ^ srow) * 8;

  const int sA0 = ((0 + ks) ^ (fr & 7)) * 8;
  const int sA1 = ((4 + ks) ^ (fr & 7)) * 8;

  f32x4 zero = {0.f, 0.f, 0.f, 0.f};
  f32x4 acc[8][4];
#pragma unroll
  for (int mi = 0; mi < 8; ++mi)
#pragma unroll
    for (int ni = 0; ni < 4; ++ni) acc[mi][ni] = zero;

  auto stA = [&](int buf, int mh, int kt) {
#pragma unroll
    for (int j = 0; j < 2; ++j) {
      int rl = mh * 128 + j * 64 + wid * 8;
      gload16(Abase + (size_t)(rl + srow) * KC + kt * GK + sch8,
              &As[buf][rl * GK]);
    }
  };
  auto stB = [&](int buf, int mh, int kt) {
#pragma unroll
    for (int j = 0; j < 2; ++j) {
      int rl = mh * 128 + j * 64 + wid * 8;
      gload16(Bbase + (size_t)(rl + srow) * KC + kt * GK + sch8,
              &Bs[buf][rl * GK]);
    }
  };

  stB(0, 0, 0); stB(0, 1, 0); stA(0, 0, 0); stA(0, 1, 0);
  asm volatile("s_waitcnt vmcnt(2)" ::: "memory");
  __builtin_amdgcn_s_barrier();

  int cur = 0;
  for (int t = 0; t < NKT; ++t) {
    const ushort* Ac = As[cur];
    const ushort* Bc = Bs[cur];
    const int nb = cur ^ 1;
    const bool pf = (t + 1 < NKT);
    bf16x8 af[4], bv[4];

    // q0: kk0, mi0-3; stage ALL of t+1
#pragma unroll
    for (int mi = 0; mi < 4; ++mi)
      af[mi] = *(const bf16x8*)&Ac[(mi * 32 + wr * 16 + fr) * GK + sA0];
#pragma unroll
    for (int ni = 0; ni < 4; ++ni)
      bv[ni] = *(const bf16x8*)&Bc[(ni * 64 + wc * 16 + fr) * GK + sA0];
    if (pf) { stB(nb, 0, t + 1); stB(nb, 1, t + 1); stA(nb, 0, t + 1); stA(nb, 1, t + 1); }
    __builtin_amdgcn_sched_barrier(0);
    __builtin_amdgcn_s_setprio(1);
#pragma unroll
    for (int mi = 0; mi < 4; ++mi)
#pragma unroll
      for (int ni = 0; ni < 4; ++ni)
        acc[mi][ni] = __builtin_amdgcn_mfma_f32_16x16x32_bf16(af[mi], bv[ni], acc[mi][ni], 0, 0, 0);
    __builtin_amdgcn_s_setprio(0);
    __builtin_amdgcn_sched_barrier(0);
    if (pf) asm volatile("s_waitcnt vmcnt(8)" ::: "memory");
    else    asm volatile("s_waitcnt vmcnt(0)" ::: "memory");
    __builtin_amdgcn_s_barrier();

    // q1: kk0, mi4-7
#pragma unroll
    for (int mi = 0; mi < 4; ++mi)
      af[mi] = *(const bf16x8*)&Ac[((mi + 4) * 32 + wr * 16 + fr) * GK + sA0];
    __builtin_amdgcn_sched_barrier(0);
    __builtin_amdgcn_s_setprio(1);
#pragma unroll
    for (int mi = 0; mi < 4; ++mi)
#pragma unroll
      for (int ni = 0; ni < 4; ++ni)
        acc[mi + 4][ni] = __builtin_amdgcn_mfma_f32_16x16x32_bf16(af[mi], bv[ni], acc[mi + 4][ni], 0, 0, 0);
    __builtin_amdgcn_s_setprio(0);
    __builtin_amdgcn_sched_barrier(0);

    // q2: kk1, mi0-3
#pragma unroll
    for (int mi = 0; mi < 4; ++mi)
      af[mi] = *(const bf16x8*)&Ac[(mi * 32 + wr * 16 + fr) * GK + sA1];
#pragma unroll
    for (int ni = 0; ni < 4; ++ni)
      bv[ni] = *(const bf16x8*)&Bc[(ni * 64 + wc * 16 + fr) * GK + sA1];
    __builtin_amdgcn_sched_barrier(0);
    __builtin_amdgcn_s_setprio(1);
#pragma unroll
    for (int mi = 0; mi < 4; ++mi)
#pragma unroll
      for (int ni = 0; ni < 4; ++ni)
        acc[mi][ni] = __builtin_amdgcn_mfma_f32_16x16x32_bf16(af[mi], bv[ni], acc[mi][ni], 0, 0, 0);
    __builtin_amdgcn_s_setprio(0);
    __builtin_amdgcn_sched_barrier(0);

    // q3: kk1, mi4-7
#pragma unroll
    for (int mi = 0; mi < 4; ++mi)
      af[mi] = *(const bf16x8*)&Ac[((mi + 4) * 32 + wr * 16 + fr) * GK + sA1];
    __builtin_amdgcn_sched_barrier(0);
    __builtin_amdgcn_s_setprio(1);
#pragma unroll
    for (int mi = 0; mi < 4; ++mi)
#pragma unroll
      for (int ni = 0; ni < 4; ++ni)
        acc[mi + 4][ni] = __builtin_amdgcn_mfma_f32_16x16x32_bf16(af[mi], bv[ni], acc[mi + 4][ni], 0, 0, 0);
    __builtin_amdgcn_s_setprio(0);
    __builtin_amdgcn_sched_barrier(0);
    if (pf) asm volatile("s_waitcnt vmcnt(2)" ::: "memory");
    __builtin_amdgcn_s_barrier();

    cur ^= 1;
  }

  const int colL = wc * 16 + fr;
  float ct = 0.f;
  if (EPI == 1) ct = __cosf(theta[colL]);
#pragma unroll
  for (int mi = 0; mi < 8; ++mi) {
    int row0 = br * GM + mi * 32 + wr * 16 + ks * 4;
#pragma unroll
    for (int ni = 0; ni < 4; ++ni) {
      size_t cbase = (size_t)row0 * N + bc * GN + ni * 64 + colL;
#pragma unroll
      for (int i = 0; i < 4; ++i) {
        if (EPI == 1)
          Cq[cbase + (size_t)i * N] = f2bf(ct * __cosf(acc[mi][ni][i]));
        else
          Cf[cbase + (size_t)i * N] = acc[mi][ni][i];
      }
    }
  }
}

// ---------------- per-token head-vs-head attention via MFMA ----------------
__global__ __launch_bounds__(256) void attn_quantum(const ushort* __restrict__ qqb,
                                                    ushort* __restrict__ aout) {
  __shared__ ushort T[4][64 * 32];
  int tid = threadIdx.x;
  int wv  = tid >> 6, l = tid & 63;
  size_t tok = (size_t)blockIdx.x * 4 + wv;
  const ushort* src = qqb + tok * NE;
  ushort* Tw = T[wv];

  int h  = l & 15;
  int kb = l >> 4;

  bf16x8 f0 = *(const bf16x8*)(src + h * 64 + kb * 8);
  bf16x8 f1 = *(const bf16x8*)(src + h * 64 + kb * 8 + 32);

#pragma unroll
  for (int jj = 0; jj < 8; ++jj) {
    int d0 = kb * 8 + jj;
    int d1 = d0 + 32;
    Tw[d0 * 32 + (((h >> 3) ^ ((d0 >> 3) & 3)) << 3) + (h & 7)] = (ushort)f0[jj];
    Tw[d1 * 32 + (((h >> 3) ^ ((d1 >> 3) & 3)) << 3) + (h & 7)] = (ushort)f1[jj];
  }

  f32x4 sa = {0.f, 0.f, 0.f, 0.f};
  sa = __builtin_amdgcn_mfma_f32_16x16x32_bf16(f0, f0, sa, 0, 0, 0);
  sa = __builtin_amdgcn_mfma_f32_16x16x32_bf16(f1, f1, sa, 0, 0, 0);

  float s[4];
#pragma unroll
  for (int i = 0; i < 4; ++i) s[i] = sa[i] * 0.125f;

  float mx = fmaxf(fmaxf(s[0], s[1]), fmaxf(s[2], s[3]));
  mx = fmaxf(mx, __shfl_xor(mx, 16));
  mx = fmaxf(mx, __shfl_xor(mx, 32));
  float e[4], sum = 0.f;
#pragma unroll
  for (int i = 0; i < 4; ++i) { e[i] = __expf(s[i] - mx); sum += e[i]; }
  sum += __shfl_xor(sum, 16);
  sum += __shfl_xor(sum, 32);
  float inv = 1.f / sum;
#pragma unroll
  for (int i = 0; i < 4; ++i) e[i] *= inv;

  int s1 = h + (kb & 1) * 32;
  float q1[4], q2[4];
#pragma unroll
  for (int i = 0; i < 4; ++i) {
    q1[i] = __shfl(e[i], s1);
    q2[i] = __shfl(e[i], s1 + 16);
  }
  bool live = (kb < 2);
  bf16x8 pa;
#pragma unroll
  for (int i = 0; i < 4; ++i) {
    pa[i]     = live ? (short)f2bf(q1[i]) : (short)0;
    pa[4 + i] = live ? (short)f2bf(q2[i]) : (short)0;
  }

  __syncthreads();

  f32x4 o[4];
#pragma unroll
  for (int c = 0; c < 4; ++c) {
    int r = c * 16 + h;
    int slot = (kb & 1) ^ ((r >> 3) & 3);
    bf16x8 bfrag = *(const bf16x8*)&Tw[r * 32 + slot * 8];
    f32x4 z = {0.f, 0.f, 0.f, 0.f};
    o[c] = __builtin_amdgcn_mfma_f32_16x16x32_bf16(pa, bfrag, z, 0, 0, 0);
  }

  ushort* dst = aout + tok * NE;
#pragma unroll
  for (int c = 0; c < 4; ++c)
#pragma unroll
    for (int i = 0; i < 4; ++i)
      dst[(kb * 4 + i) * NDK + c * 16 + h] = f2bf(o[c][i]);
}

// ---------------- launch ----------------
extern "C" void kernel_launch(void* const* d_in, const int* in_sizes, int n_in,
                              void* d_out, int out_size, void* d_ws, size_t ws_size,
                              hipStream_t stream) {
  const float* x     = (const float*)d_in[0];
  const float* W     = (const float*)d_in[1];
  const float* theta = (const float*)d_in[2];
  float* out = (float*)d_out;

  char* ws = (char*)d_ws;
  ushort* Wb   = (ushort*)ws;                                   // 2 MB
  ushort* qqb  = (ushort*)(ws + (size_t)NE * NE * 2);           // 32 MB
  ushort* aout = (ushort*)(ws + (size_t)NE * NE * 2 + (size_t)MTOK * NE * 2); // 32 MB

  cvt_bf16<<<256, 256, 0, stream>>>(W, Wb, NE * NE / 4);

  // GEMM1: A = x (f32, reg-staged 2-ahead + fused cvt), fused quantum-cos
  gemm_xq<<<(MTOK / QM) * (NE / QN), 512, 0, stream>>>(x, Wb, qqb, theta);

  attn_quantum<<<MTOK / 4, 256, 0, stream>>>(qqb, aout);

  // GEMM2: A = aout (bf16 gload_lds), f32 out (r13 proven kernel)
  gemm256<0><<<(MTOK / GM) * (NE / GN), 512, 0, stream>>>(aout, Wb, out, nullptr, nullptr, MTOK, NE, NE);
}